// Round 1
// baseline (2589.818 us; speedup 1.0000x reference)
//
#include <hip/hip_runtime.h>
#include <cstdint>
#include <cstddef>

typedef short s8v __attribute__((ext_vector_type(8)));
typedef short s4v __attribute__((ext_vector_type(4)));
typedef float f4v __attribute__((ext_vector_type(4)));

static __device__ __forceinline__ float b2f(short s){
  return __uint_as_float(((uint32_t)(uint16_t)s) << 16);
}
static __device__ __forceinline__ short f2bf(float f){
  uint32_t u = __float_as_uint(f);
  u = (u + 0x7fffu + ((u >> 16) & 1u)) >> 16;
  return (short)(uint16_t)u;
}

// ---- graph prep ----
__global__ void k_deg(const int* __restrict__ tgt, int* __restrict__ deg, int nE){
  int e = blockIdx.x*blockDim.x + threadIdx.x;
  if(e < nE) atomicAdd(&deg[tgt[e]], 1);
}
__global__ void k_cnt(const int* __restrict__ batch, float* __restrict__ cnt, int nN){
  int i = blockIdx.x*blockDim.x + threadIdx.x;
  if(i < nN) atomicAdd(&cnt[batch[i]], 1.0f);
}
__global__ void k_dinv(const int* __restrict__ deg, float* __restrict__ dinv, int nN){
  int i = blockIdx.x*blockDim.x + threadIdx.x;
  if(i < nN) dinv[i] = rsqrtf((float)deg[i] + 1.0f); // +1 self-loop
}
// WT[n][k] = bf16(W[k][n])
__global__ void k_transpose_cvt(const float* __restrict__ W, short* __restrict__ WT, int K, int N){
  int g = blockIdx.x*blockDim.x + threadIdx.x;
  if(g >= K*N) return;
  int n = g / K, k = g % K;
  WT[(size_t)n*K + k] = f2bf(W[(size_t)k*N + n]);
}

// ---- bf16 MFMA GEMM: C[m][n] = sum_k A[m][k] * Bt[n][k]; C stored bf16 ----
template<bool AF32>
__global__ __launch_bounds__(256) void gemm_bt(const void* __restrict__ Ap,
    const short* __restrict__ Bt, short* __restrict__ C, int M, int N, int K)
{
  constexpr int BM=128, BN=128, BK=32, PAD=8;
  __shared__ short As[BM][BK+PAD];
  __shared__ short Bs[BN][BK+PAD];
  const int tid  = threadIdx.x;
  const int lane = tid & 63;
  const int wave = tid >> 6;
  const int wm = (wave >> 1) * 64;
  const int wn = (wave & 1) * 64;
  const int row0 = blockIdx.x * BM;
  const int col0 = blockIdx.y * BN;

  f4v acc[4][4];
  #pragma unroll
  for(int i=0;i<4;i++)
    #pragma unroll
    for(int j=0;j<4;j++){ acc[i][j][0]=0.f; acc[i][j][1]=0.f; acc[i][j][2]=0.f; acc[i][j][3]=0.f; }

  const int sr = tid >> 1;        // staging row (A) / col (Bt), 0..127
  const int sk = (tid & 1) * 16;  // staging k offset

  for(int k0=0; k0<K; k0+=BK){
    // stage A (convert f32->bf16 on the fly for layer-1 input)
    if constexpr(AF32){
      const float* A = (const float*)Ap;
      int gr = row0 + sr;
      float vf[16];
      if(gr < M){
        const float* p = A + (size_t)gr * K + k0 + sk;
        #pragma unroll
        for(int i=0;i<4;i++){
          f4v t = *(const f4v*)(p + i*4);
          vf[i*4+0]=t[0]; vf[i*4+1]=t[1]; vf[i*4+2]=t[2]; vf[i*4+3]=t[3];
        }
      } else {
        #pragma unroll
        for(int i=0;i<16;i++) vf[i]=0.f;
      }
      s8v v0, v1;
      #pragma unroll
      for(int i=0;i<8;i++){ v0[i] = f2bf(vf[i]); v1[i] = f2bf(vf[8+i]); }
      *(s8v*)&As[sr][sk]   = v0;
      *(s8v*)&As[sr][sk+8] = v1;
    } else {
      const short* A = (const short*)Ap;
      int gr = row0 + sr;
      s8v v0, v1;
      if(gr < M){
        const short* p = A + (size_t)gr * K + k0 + sk;
        v0 = *(const s8v*)p; v1 = *(const s8v*)(p+8);
      } else {
        #pragma unroll
        for(int i=0;i<8;i++){ v0[i]=0; v1[i]=0; }
      }
      *(s8v*)&As[sr][sk]   = v0;
      *(s8v*)&As[sr][sk+8] = v1;
    }
    // stage Bt (always bf16, full tiles: N=256 multiple of 128, K mult of 32)
    {
      const short* p = Bt + (size_t)(col0 + sr) * K + k0 + sk;
      *(s8v*)&Bs[sr][sk]   = *(const s8v*)p;
      *(s8v*)&Bs[sr][sk+8] = *(const s8v*)(p+8);
    }
    __syncthreads();

    const int kq = (lane >> 4) * 8;
    const int lr = lane & 15;
    s8v af[4], bfr[4];
    #pragma unroll
    for(int mf=0; mf<4; mf++) af[mf]  = *(const s8v*)&As[wm + mf*16 + lr][kq];
    #pragma unroll
    for(int nf=0; nf<4; nf++) bfr[nf] = *(const s8v*)&Bs[wn + nf*16 + lr][kq];
    #pragma unroll
    for(int mf=0; mf<4; mf++)
      #pragma unroll
      for(int nf=0; nf<4; nf++)
        acc[mf][nf] = __builtin_amdgcn_mfma_f32_16x16x32_bf16(af[mf], bfr[nf], acc[mf][nf], 0, 0, 0);
    __syncthreads();
  }

  const int lr = lane & 15, lq = lane >> 4;
  #pragma unroll
  for(int mf=0; mf<4; mf++){
    #pragma unroll
    for(int j=0;j<4;j++){
      int row = row0 + wm + mf*16 + lq*4 + j;
      if(row >= M) continue;
      #pragma unroll
      for(int nf=0; nf<4; nf++){
        int col = col0 + wn + nf*16 + lr;
        C[(size_t)row*N + col] = f2bf(acc[mf][nf][j]);
      }
    }
  }
}

// ---- aggregation ----
// agg[i][c] = dinv[i]^2 * h[i][c]   (self-loop term; also serves as the zero-init)
__global__ void k_agg_init(const short* __restrict__ h, const float* __restrict__ dinv,
                           float* __restrict__ agg){
  int i = blockIdx.x, c = threadIdx.x;
  float d2 = dinv[i]*dinv[i];
  agg[(size_t)i*256 + c] = d2 * b2f(h[(size_t)i*256 + c]);
}
// one wave per edge, 4 channels/lane, scatter atomics
__global__ void k_agg_edge(const int* __restrict__ src, const int* __restrict__ tgt,
                           const float* __restrict__ dinv, const short* __restrict__ h,
                           float* __restrict__ agg, int nE){
  int idx = blockIdx.x*blockDim.x + threadIdx.x;
  int e = idx >> 6;
  int lane = idx & 63;
  if(e >= nE) return;
  int s = src[e], t = tgt[e];
  float w = dinv[s]*dinv[t];
  s4v v = *(const s4v*)&h[(size_t)s*256 + lane*4];
  float* dst = &agg[(size_t)t*256 + lane*4];
  #pragma unroll
  for(int j=0;j<4;j++) atomicAdd(dst+j, w * b2f(v[j]));
}
// hout[i][c] = bf16(relu(agg[i][c] + b[c]))
__global__ void k_post(const float* __restrict__ agg, const float* __restrict__ b,
                       short* __restrict__ hout){
  int i = blockIdx.x, c = threadIdx.x;
  float v = agg[(size_t)i*256 + c] + b[c];
  hout[(size_t)i*256 + c] = f2bf(fmaxf(v, 0.f));
}
// layer-2 epilogue fused with mean-pool accumulation
__global__ void k_post_pool(const float* __restrict__ agg, const float* __restrict__ b,
                            const int* __restrict__ batch, float* __restrict__ pool){
  int i = blockIdx.x, c = threadIdx.x;
  float v = fmaxf(agg[(size_t)i*256 + c] + b[c], 0.f);
  atomicAdd(&pool[(size_t)batch[i]*256 + c], v);
}
// out[g][j] = (pool[g]/cnt[g]) @ Wp + bp
__global__ void k_final(const float* __restrict__ pool, const float* __restrict__ cnt,
                        const float* __restrict__ Wp, const float* __restrict__ bp,
                        float* __restrict__ out, int HID_, int OUT_){
  __shared__ float mean[256];
  int g = blockIdx.x, j = threadIdx.x;
  float c = fmaxf(cnt[g], 1.0f);
  for(int k=j; k<HID_; k+=blockDim.x) mean[k] = pool[(size_t)g*HID_ + k] / c;
  __syncthreads();
  float acc = bp[j];
  for(int k=0;k<HID_;k++) acc = fmaf(mean[k], Wp[(size_t)k*OUT_ + j], acc);
  out[(size_t)g*OUT_ + j] = acc;
}

extern "C" void kernel_launch(void* const* d_in, const int* in_sizes, int n_in,
                              void* d_out, int out_size, void* d_ws, size_t ws_size,
                              hipStream_t stream){
  const float* x   = (const float*)d_in[0];
  const int* ei    = (const int*)d_in[1];
  const int* batch = (const int*)d_in[2];
  const float* W1  = (const float*)d_in[3];
  const float* b1  = (const float*)d_in[4];
  const float* W2  = (const float*)d_in[5];
  const float* b2  = (const float*)d_in[6];
  const float* Wp  = (const float*)d_in[7];
  const float* bp  = (const float*)d_in[8];
  float* out = (float*)d_out;

  const int HID    = in_sizes[4];            // 256
  const int IN_DIM = in_sizes[3] / HID;      // 768
  const int OUT    = in_sizes[8];            // 128
  const int nE     = in_sizes[1] / 2;        // 300000
  const int nN     = in_sizes[2];            // 50000
  const int nG     = out_size / OUT;         // 64

  const int* src = ei;
  const int* tgt = ei + nE;

  char* w = (char*)d_ws;
  size_t off = 0;
  auto alloc = [&](size_t bytes)->char*{
    char* p = w + off; off += (bytes + 511) & ~(size_t)511; return p;
  };
  int*   deg  = (int*)  alloc((size_t)nN*4);
  float* dinv = (float*)alloc((size_t)nN*4);
  float* cnt  = (float*)alloc((size_t)nG*4);
  float* pool = (float*)alloc((size_t)nG*HID*4);
  short* W1T  = (short*)alloc((size_t)IN_DIM*HID*2);
  short* W2T  = (short*)alloc((size_t)HID*HID*2);
  short* h1   = (short*)alloc((size_t)nN*HID*2);
  short* h2   = (short*)alloc((size_t)nN*HID*2);
  float* agg  = (float*)alloc((size_t)nN*HID*4);
  (void)ws_size; (void)n_in;

  hipMemsetAsync(deg,  0, (size_t)nN*4, stream);
  hipMemsetAsync(cnt,  0, (size_t)nG*4, stream);
  hipMemsetAsync(pool, 0, (size_t)nG*HID*4, stream);

  k_deg <<<(nE+255)/256, 256, 0, stream>>>(tgt, deg, nE);
  k_cnt <<<(nN+255)/256, 256, 0, stream>>>(batch, cnt, nN);
  k_dinv<<<(nN+255)/256, 256, 0, stream>>>(deg, dinv, nN);
  k_transpose_cvt<<<(IN_DIM*HID+255)/256, 256, 0, stream>>>(W1, W1T, IN_DIM, HID);
  k_transpose_cvt<<<(HID*HID+255)/256,   256, 0, stream>>>(W2, W2T, HID, HID);

  dim3 g1((nN+127)/128, HID/128);
  // layer 1
  gemm_bt<true><<<g1, 256, 0, stream>>>(x, W1T, h1, nN, HID, IN_DIM);
  k_agg_init<<<nN, HID, 0, stream>>>(h1, dinv, agg);
  k_agg_edge<<<(size_t)nE*64/256, 256, 0, stream>>>(src, tgt, dinv, h1, agg, nE);
  k_post<<<nN, HID, 0, stream>>>(agg, b1, h1);      // h1 := relu(layer1), bf16
  // layer 2
  gemm_bt<false><<<g1, 256, 0, stream>>>(h1, W2T, h2, nN, HID, HID);
  k_agg_init<<<nN, HID, 0, stream>>>(h2, dinv, agg);
  k_agg_edge<<<(size_t)nE*64/256, 256, 0, stream>>>(src, tgt, dinv, h2, agg, nE);
  k_post_pool<<<nN, HID, 0, stream>>>(agg, b2, batch, pool);
  // head
  k_final<<<nG, OUT, 0, stream>>>(pool, cnt, Wp, bp, out, HID, OUT);
}

// Round 2
// 855.476 us; speedup vs baseline: 3.0273x; 3.0273x over previous
//
#include <hip/hip_runtime.h>
#include <cstdint>
#include <cstddef>

typedef short s8v __attribute__((ext_vector_type(8)));
typedef short s4v __attribute__((ext_vector_type(4)));
typedef float f4v __attribute__((ext_vector_type(4)));

static __device__ __forceinline__ float b2f(short s){
  return __uint_as_float(((uint32_t)(uint16_t)s) << 16);
}
static __device__ __forceinline__ short f2bf(float f){
  uint32_t u = __float_as_uint(f);
  u = (u + 0x7fffu + ((u >> 16) & 1u)) >> 16;
  return (short)(uint16_t)u;
}

// ---- graph prep ----
__global__ void k_deg(const int* __restrict__ tgt, int* __restrict__ deg, int nE){
  int e = blockIdx.x*blockDim.x + threadIdx.x;
  if(e < nE) atomicAdd(&deg[tgt[e]], 1);
}
__global__ void k_cnt(const int* __restrict__ batch, float* __restrict__ cnt, int nN){
  int i = blockIdx.x*blockDim.x + threadIdx.x;
  if(i < nN) atomicAdd(&cnt[batch[i]], 1.0f);
}
__global__ void k_dinv(const int* __restrict__ deg, float* __restrict__ dinv, int nN){
  int i = blockIdx.x*blockDim.x + threadIdx.x;
  if(i < nN) dinv[i] = rsqrtf((float)deg[i] + 1.0f); // +1 self-loop
}
// WT[n][k] = bf16(W[k][n])
__global__ void k_transpose_cvt(const float* __restrict__ W, short* __restrict__ WT, int K, int N){
  int g = blockIdx.x*blockDim.x + threadIdx.x;
  if(g >= K*N) return;
  int n = g / K, k = g % K;
  WT[(size_t)n*K + k] = f2bf(W[(size_t)k*N + n]);
}

// ---- CSR build: exclusive scan of deg -> rowptr, then cursor fill ----
#define SCAN_BS 256
// block-local exclusive scan; rowptr[i] = in-block exclusive; blocksum[b] = block total
__global__ void k_scan1(const int* __restrict__ deg, int* __restrict__ rowptr,
                        int* __restrict__ blocksum, int nN){
  __shared__ int tmp[SCAN_BS];
  const int t = threadIdx.x;
  const int i = blockIdx.x*SCAN_BS + t;
  int v = (i < nN) ? deg[i] : 0;
  tmp[t] = v; __syncthreads();
  #pragma unroll
  for(int off=1; off<SCAN_BS; off<<=1){
    int x = (t >= off) ? tmp[t-off] : 0;
    __syncthreads();
    tmp[t] += x;
    __syncthreads();
  }
  if(i < nN) rowptr[i] = tmp[t] - v;
  if(t == SCAN_BS-1) blocksum[blockIdx.x] = tmp[t];
}
// single-block exclusive scan of blocksums (nb <= 1024)
__global__ void k_scan2(int* __restrict__ blocksum, int nb){
  __shared__ int tmp[1024];
  const int t = threadIdx.x;
  int v = (t < nb) ? blocksum[t] : 0;
  tmp[t] = v; __syncthreads();
  #pragma unroll
  for(int off=1; off<1024; off<<=1){
    int x = (t >= off) ? tmp[t-off] : 0;
    __syncthreads();
    tmp[t] += x;
    __syncthreads();
  }
  if(t < nb) blocksum[t] = tmp[t] - v;
}
__global__ void k_scan3(int* __restrict__ rowptr, const int* __restrict__ blocksum,
                        int nN, int nE){
  const int i = blockIdx.x*SCAN_BS + threadIdx.x;
  if(i < nN) rowptr[i] += blocksum[blockIdx.x];
  if(i == 0) rowptr[nN] = nE;
}
__global__ void k_fill(const int* __restrict__ src, const int* __restrict__ tgt,
                       const int* __restrict__ rowptr, int* __restrict__ cursor,
                       int* __restrict__ csr_src, int nE){
  int e = blockIdx.x*blockDim.x + threadIdx.x;
  if(e >= nE) return;
  int t = tgt[e];
  int pos = rowptr[t] + atomicAdd(&cursor[t], 1);
  csr_src[pos] = src[e];
}

// ---- bf16 MFMA GEMM: C[m][n] = sum_k A[m][k] * Bt[n][k]; C stored bf16 ----
template<bool AF32>
__global__ __launch_bounds__(256) void gemm_bt(const void* __restrict__ Ap,
    const short* __restrict__ Bt, short* __restrict__ C, int M, int N, int K)
{
  constexpr int BM=128, BN=128, BK=32, PAD=8;
  __shared__ short As[BM][BK+PAD];
  __shared__ short Bs[BN][BK+PAD];
  const int tid  = threadIdx.x;
  const int lane = tid & 63;
  const int wave = tid >> 6;
  const int wm = (wave >> 1) * 64;
  const int wn = (wave & 1) * 64;
  const int row0 = blockIdx.x * BM;
  const int col0 = blockIdx.y * BN;

  f4v acc[4][4];
  #pragma unroll
  for(int i=0;i<4;i++)
    #pragma unroll
    for(int j=0;j<4;j++){ acc[i][j][0]=0.f; acc[i][j][1]=0.f; acc[i][j][2]=0.f; acc[i][j][3]=0.f; }

  const int sr = tid >> 1;        // staging row (A) / col (Bt), 0..127
  const int sk = (tid & 1) * 16;  // staging k offset

  for(int k0=0; k0<K; k0+=BK){
    if constexpr(AF32){
      const float* A = (const float*)Ap;
      int gr = row0 + sr;
      float vf[16];
      if(gr < M){
        const float* p = A + (size_t)gr * K + k0 + sk;
        #pragma unroll
        for(int i=0;i<4;i++){
          f4v t = *(const f4v*)(p + i*4);
          vf[i*4+0]=t[0]; vf[i*4+1]=t[1]; vf[i*4+2]=t[2]; vf[i*4+3]=t[3];
        }
      } else {
        #pragma unroll
        for(int i=0;i<16;i++) vf[i]=0.f;
      }
      s8v v0, v1;
      #pragma unroll
      for(int i=0;i<8;i++){ v0[i] = f2bf(vf[i]); v1[i] = f2bf(vf[8+i]); }
      *(s8v*)&As[sr][sk]   = v0;
      *(s8v*)&As[sr][sk+8] = v1;
    } else {
      const short* A = (const short*)Ap;
      int gr = row0 + sr;
      s8v v0, v1;
      if(gr < M){
        const short* p = A + (size_t)gr * K + k0 + sk;
        v0 = *(const s8v*)p; v1 = *(const s8v*)(p+8);
      } else {
        #pragma unroll
        for(int i=0;i<8;i++){ v0[i]=0; v1[i]=0; }
      }
      *(s8v*)&As[sr][sk]   = v0;
      *(s8v*)&As[sr][sk+8] = v1;
    }
    {
      const short* p = Bt + (size_t)(col0 + sr) * K + k0 + sk;
      *(s8v*)&Bs[sr][sk]   = *(const s8v*)p;
      *(s8v*)&Bs[sr][sk+8] = *(const s8v*)(p+8);
    }
    __syncthreads();

    const int kq = (lane >> 4) * 8;
    const int lr = lane & 15;
    s8v af[4], bfr[4];
    #pragma unroll
    for(int mf=0; mf<4; mf++) af[mf]  = *(const s8v*)&As[wm + mf*16 + lr][kq];
    #pragma unroll
    for(int nf=0; nf<4; nf++) bfr[nf] = *(const s8v*)&Bs[wn + nf*16 + lr][kq];
    #pragma unroll
    for(int mf=0; mf<4; mf++)
      #pragma unroll
      for(int nf=0; nf<4; nf++)
        acc[mf][nf] = __builtin_amdgcn_mfma_f32_16x16x32_bf16(af[mf], bfr[nf], acc[mf][nf], 0, 0, 0);
    __syncthreads();
  }

  const int lr = lane & 15, lq = lane >> 4;
  #pragma unroll
  for(int mf=0; mf<4; mf++){
    #pragma unroll
    for(int j=0;j<4;j++){
      int row = row0 + wm + mf*16 + lq*4 + j;
      if(row >= M) continue;
      #pragma unroll
      for(int nf=0; nf<4; nf++){
        int col = col0 + wn + nf*16 + lr;
        C[(size_t)row*N + col] = f2bf(acc[mf][nf][j]);
      }
    }
  }
}

// ---- fused aggregation: one wave per node ----
// out_node = relu( dinv[i]^2*h[i] + sum_{s in N(i)} dinv[i]*dinv[s]*h[s] + b )
// POOL: additionally atomicAdd into pool[batch[i]] (and skip hout write)
template<bool POOL>
__global__ __launch_bounds__(256) void k_aggregate(
    const short* __restrict__ h, const float* __restrict__ dinv,
    const int* __restrict__ rowptr, const int* __restrict__ csr_src,
    const float* __restrict__ bias, const int* __restrict__ batch,
    short* __restrict__ hout, float* __restrict__ pool, int nN)
{
  const int wave = threadIdx.x >> 6;
  const int lane = threadIdx.x & 63;
  const int node = blockIdx.x*4 + wave;
  if(node >= nN) return;
  const float di = dinv[node];
  const int beg = rowptr[node], end = rowptr[node+1];

  s4v hv = *(const s4v*)&h[(size_t)node*256 + lane*4];
  const float d2 = di*di;
  f4v acc;
  #pragma unroll
  for(int j=0;j<4;j++) acc[j] = d2 * b2f(hv[j]);

  for(int p=beg; p<end; p++){
    int s = csr_src[p];
    float w = di * dinv[s];
    s4v v = *(const s4v*)&h[(size_t)s*256 + lane*4];
    #pragma unroll
    for(int j=0;j<4;j++) acc[j] += w * b2f(v[j]);
  }

  f4v bv = *(const f4v*)&bias[lane*4];
  if constexpr(POOL){
    int g = batch[node];
    float* dst = &pool[(size_t)g*256 + lane*4];
    #pragma unroll
    for(int j=0;j<4;j++) atomicAdd(dst+j, fmaxf(acc[j]+bv[j], 0.f));
  } else {
    s4v ov;
    #pragma unroll
    for(int j=0;j<4;j++) ov[j] = f2bf(fmaxf(acc[j]+bv[j], 0.f));
    *(s4v*)&hout[(size_t)node*256 + lane*4] = ov;
  }
}

// out[g][j] = (pool[g]/cnt[g]) @ Wp + bp
__global__ void k_final(const float* __restrict__ pool, const float* __restrict__ cnt,
                        const float* __restrict__ Wp, const float* __restrict__ bp,
                        float* __restrict__ out, int HID_, int OUT_){
  __shared__ float mean[256];
  int g = blockIdx.x, j = threadIdx.x;
  float c = fmaxf(cnt[g], 1.0f);
  for(int k=j; k<HID_; k+=blockDim.x) mean[k] = pool[(size_t)g*HID_ + k] / c;
  __syncthreads();
  float acc = bp[j];
  for(int k=0;k<HID_;k++) acc = fmaf(mean[k], Wp[(size_t)k*OUT_ + j], acc);
  out[(size_t)g*OUT_ + j] = acc;
}

extern "C" void kernel_launch(void* const* d_in, const int* in_sizes, int n_in,
                              void* d_out, int out_size, void* d_ws, size_t ws_size,
                              hipStream_t stream){
  const float* x   = (const float*)d_in[0];
  const int* ei    = (const int*)d_in[1];
  const int* batch = (const int*)d_in[2];
  const float* W1  = (const float*)d_in[3];
  const float* b1  = (const float*)d_in[4];
  const float* W2  = (const float*)d_in[5];
  const float* b2  = (const float*)d_in[6];
  const float* Wp  = (const float*)d_in[7];
  const float* bp  = (const float*)d_in[8];
  float* out = (float*)d_out;

  const int HID    = in_sizes[4];            // 256
  const int IN_DIM = in_sizes[3] / HID;      // 768
  const int OUT    = in_sizes[8];            // 128
  const int nE     = in_sizes[1] / 2;        // 300000
  const int nN     = in_sizes[2];            // 50000
  const int nG     = out_size / OUT;         // 64

  const int* src = ei;
  const int* tgt = ei + nE;

  char* w = (char*)d_ws;
  size_t off = 0;
  auto alloc = [&](size_t bytes)->char*{
    char* p = w + off; off += (bytes + 511) & ~(size_t)511; return p;
  };
  int*   deg     = (int*)  alloc((size_t)nN*4);
  float* dinv    = (float*)alloc((size_t)nN*4);
  float* cnt     = (float*)alloc((size_t)nG*4);
  float* pool    = (float*)alloc((size_t)nG*HID*4);
  int*   rowptr  = (int*)  alloc((size_t)(nN+1)*4);
  int*   cursor  = (int*)  alloc((size_t)nN*4);
  int*   csr_src = (int*)  alloc((size_t)nE*4);
  int*   blocksum= (int*)  alloc((size_t)1024*4);
  short* W1T     = (short*)alloc((size_t)IN_DIM*HID*2);
  short* W2T     = (short*)alloc((size_t)HID*HID*2);
  short* h1      = (short*)alloc((size_t)nN*HID*2);
  short* h2      = (short*)alloc((size_t)nN*HID*2);
  (void)ws_size; (void)n_in;

  hipMemsetAsync(deg,    0, (size_t)nN*4, stream);
  hipMemsetAsync(cursor, 0, (size_t)nN*4, stream);
  hipMemsetAsync(cnt,    0, (size_t)nG*4, stream);
  hipMemsetAsync(pool,   0, (size_t)nG*HID*4, stream);

  const int nb = (nN + SCAN_BS - 1) / SCAN_BS;   // 196 blocks
  k_deg <<<(nE+255)/256, 256, 0, stream>>>(tgt, deg, nE);
  k_cnt <<<(nN+255)/256, 256, 0, stream>>>(batch, cnt, nN);
  k_dinv<<<(nN+255)/256, 256, 0, stream>>>(deg, dinv, nN);
  k_scan1<<<nb, SCAN_BS, 0, stream>>>(deg, rowptr, blocksum, nN);
  k_scan2<<<1, 1024, 0, stream>>>(blocksum, nb);
  k_scan3<<<nb, SCAN_BS, 0, stream>>>(rowptr, blocksum, nN, nE);
  k_fill <<<(nE+255)/256, 256, 0, stream>>>(src, tgt, rowptr, cursor, csr_src, nE);
  k_transpose_cvt<<<(IN_DIM*HID+255)/256, 256, 0, stream>>>(W1, W1T, IN_DIM, HID);
  k_transpose_cvt<<<(HID*HID+255)/256,   256, 0, stream>>>(W2, W2T, HID, HID);

  dim3 g1((nN+127)/128, HID/128);
  const int nagg = (nN + 3) / 4;
  // layer 1: GEMM -> fused aggregate+bias+relu -> h1
  gemm_bt<true><<<g1, 256, 0, stream>>>(x, W1T, h2, nN, HID, IN_DIM);   // h2 = x@W1 (pre-agg)
  k_aggregate<false><<<nagg, 256, 0, stream>>>(h2, dinv, rowptr, csr_src, b1, batch, h1, pool, nN);
  // layer 2: GEMM -> fused aggregate+bias+relu+pool
  gemm_bt<false><<<g1, 256, 0, stream>>>(h1, W2T, h2, nN, HID, HID);
  k_aggregate<true><<<nagg, 256, 0, stream>>>(h2, dinv, rowptr, csr_src, b2, batch, h1, pool, nN);
  // head
  k_final<<<nG, OUT, 0, stream>>>(pool, cnt, Wp, bp, out, HID, OUT);
}

// Round 3
// 265.375 us; speedup vs baseline: 9.7591x; 3.2237x over previous
//
#include <hip/hip_runtime.h>
#include <cstdint>
#include <cstddef>

typedef short s8v __attribute__((ext_vector_type(8)));
typedef short s4v __attribute__((ext_vector_type(4)));
typedef float f4v __attribute__((ext_vector_type(4)));

static __device__ __forceinline__ float b2f(short s){
  return __uint_as_float(((uint32_t)(uint16_t)s) << 16);
}
static __device__ __forceinline__ short f2bf(float f){
  uint32_t u = __float_as_uint(f);
  u = (u + 0x7fffu + ((u >> 16) & 1u)) >> 16;
  return (short)(uint16_t)u;
}

// ---- graph prep ----
__global__ void k_deg(const int* __restrict__ tgt, int* __restrict__ deg, int nE){
  int e = blockIdx.x*blockDim.x + threadIdx.x;
  if(e < nE) atomicAdd(&deg[tgt[e]], 1);
}
__global__ void k_dinv(const int* __restrict__ deg, float* __restrict__ dinv, int nN){
  int i = blockIdx.x*blockDim.x + threadIdx.x;
  if(i < nN) dinv[i] = rsqrtf((float)deg[i] + 1.0f); // +1 self-loop
}
// WT[n][k] = bf16(W[k][n])
__global__ void k_transpose_cvt(const float* __restrict__ W, short* __restrict__ WT, int K, int N){
  int g = blockIdx.x*blockDim.x + threadIdx.x;
  if(g >= K*N) return;
  int n = g / K, k = g % K;
  WT[(size_t)n*K + k] = f2bf(W[(size_t)k*N + n]);
}
// graph boundaries in sorted batch: gstart[g] = first i with batch[i] >= g
__global__ void k_bounds(const int* __restrict__ batch, int* __restrict__ gstart,
                         int nN, int nG){
  int g = threadIdx.x;
  if(g > nG) return;
  int lo = 0, hi = nN;
  while(lo < hi){
    int mid = (lo + hi) >> 1;
    if(batch[mid] < g) lo = mid + 1; else hi = mid;
  }
  gstart[g] = lo;
}

// ---- CSR build: exclusive scan of deg -> rowptr, then cursor fill ----
#define SCAN_BS 256
__global__ void k_scan1(const int* __restrict__ deg, int* __restrict__ rowptr,
                        int* __restrict__ blocksum, int nN){
  __shared__ int tmp[SCAN_BS];
  const int t = threadIdx.x;
  const int i = blockIdx.x*SCAN_BS + t;
  int v = (i < nN) ? deg[i] : 0;
  tmp[t] = v; __syncthreads();
  #pragma unroll
  for(int off=1; off<SCAN_BS; off<<=1){
    int x = (t >= off) ? tmp[t-off] : 0;
    __syncthreads();
    tmp[t] += x;
    __syncthreads();
  }
  if(i < nN) rowptr[i] = tmp[t] - v;
  if(t == SCAN_BS-1) blocksum[blockIdx.x] = tmp[t];
}
__global__ void k_scan2(int* __restrict__ blocksum, int nb){
  __shared__ int tmp[1024];
  const int t = threadIdx.x;
  int v = (t < nb) ? blocksum[t] : 0;
  tmp[t] = v; __syncthreads();
  #pragma unroll
  for(int off=1; off<1024; off<<=1){
    int x = (t >= off) ? tmp[t-off] : 0;
    __syncthreads();
    tmp[t] += x;
    __syncthreads();
  }
  if(t < nb) blocksum[t] = tmp[t] - v;
}
__global__ void k_scan3(int* __restrict__ rowptr, const int* __restrict__ blocksum,
                        int nN, int nE){
  const int i = blockIdx.x*SCAN_BS + threadIdx.x;
  if(i < nN) rowptr[i] += blocksum[blockIdx.x];
  if(i == 0) rowptr[nN] = nE;
}
__global__ void k_fill(const int* __restrict__ src, const int* __restrict__ tgt,
                       const int* __restrict__ rowptr, int* __restrict__ cursor,
                       int* __restrict__ csr_src, int nE){
  int e = blockIdx.x*blockDim.x + threadIdx.x;
  if(e >= nE) return;
  int t = tgt[e];
  int pos = rowptr[t] + atomicAdd(&cursor[t], 1);
  csr_src[pos] = src[e];
}

// ---- bf16 MFMA GEMM: C[m][n] = sum_k A[m][k] * Bt[n][k]; C stored bf16 ----
template<bool AF32>
__global__ __launch_bounds__(256) void gemm_bt(const void* __restrict__ Ap,
    const short* __restrict__ Bt, short* __restrict__ C, int M, int N, int K)
{
  constexpr int BM=128, BN=128, BK=32, PAD=8;
  __shared__ short As[BM][BK+PAD];
  __shared__ short Bs[BN][BK+PAD];
  const int tid  = threadIdx.x;
  const int lane = tid & 63;
  const int wave = tid >> 6;
  const int wm = (wave >> 1) * 64;
  const int wn = (wave & 1) * 64;
  const int row0 = blockIdx.x * BM;
  const int col0 = blockIdx.y * BN;

  f4v acc[4][4];
  #pragma unroll
  for(int i=0;i<4;i++)
    #pragma unroll
    for(int j=0;j<4;j++){ acc[i][j][0]=0.f; acc[i][j][1]=0.f; acc[i][j][2]=0.f; acc[i][j][3]=0.f; }

  const int sr = tid >> 1;        // staging row (A) / col (Bt), 0..127
  const int sk = (tid & 1) * 16;  // staging k offset

  for(int k0=0; k0<K; k0+=BK){
    if constexpr(AF32){
      const float* A = (const float*)Ap;
      int gr = row0 + sr;
      float vf[16];
      if(gr < M){
        const float* p = A + (size_t)gr * K + k0 + sk;
        #pragma unroll
        for(int i=0;i<4;i++){
          f4v t = *(const f4v*)(p + i*4);
          vf[i*4+0]=t[0]; vf[i*4+1]=t[1]; vf[i*4+2]=t[2]; vf[i*4+3]=t[3];
        }
      } else {
        #pragma unroll
        for(int i=0;i<16;i++) vf[i]=0.f;
      }
      s8v v0, v1;
      #pragma unroll
      for(int i=0;i<8;i++){ v0[i] = f2bf(vf[i]); v1[i] = f2bf(vf[8+i]); }
      *(s8v*)&As[sr][sk]   = v0;
      *(s8v*)&As[sr][sk+8] = v1;
    } else {
      const short* A = (const short*)Ap;
      int gr = row0 + sr;
      s8v v0, v1;
      if(gr < M){
        const short* p = A + (size_t)gr * K + k0 + sk;
        v0 = *(const s8v*)p; v1 = *(const s8v*)(p+8);
      } else {
        #pragma unroll
        for(int i=0;i<8;i++){ v0[i]=0; v1[i]=0; }
      }
      *(s8v*)&As[sr][sk]   = v0;
      *(s8v*)&As[sr][sk+8] = v1;
    }
    {
      const short* p = Bt + (size_t)(col0 + sr) * K + k0 + sk;
      *(s8v*)&Bs[sr][sk]   = *(const s8v*)p;
      *(s8v*)&Bs[sr][sk+8] = *(const s8v*)(p+8);
    }
    __syncthreads();

    const int kq = (lane >> 4) * 8;
    const int lr = lane & 15;
    s8v af[4], bfr[4];
    #pragma unroll
    for(int mf=0; mf<4; mf++) af[mf]  = *(const s8v*)&As[wm + mf*16 + lr][kq];
    #pragma unroll
    for(int nf=0; nf<4; nf++) bfr[nf] = *(const s8v*)&Bs[wn + nf*16 + lr][kq];
    #pragma unroll
    for(int mf=0; mf<4; mf++)
      #pragma unroll
      for(int nf=0; nf<4; nf++)
        acc[mf][nf] = __builtin_amdgcn_mfma_f32_16x16x32_bf16(af[mf], bfr[nf], acc[mf][nf], 0, 0, 0);
    __syncthreads();
  }

  const int lr = lane & 15, lq = lane >> 4;
  #pragma unroll
  for(int mf=0; mf<4; mf++){
    #pragma unroll
    for(int j=0;j<4;j++){
      int row = row0 + wm + mf*16 + lq*4 + j;
      if(row >= M) continue;
      #pragma unroll
      for(int nf=0; nf<4; nf++){
        int col = col0 + wn + nf*16 + lr;
        C[(size_t)row*N + col] = f2bf(acc[mf][nf][j]);
      }
    }
  }
}

// ---- fused aggregation: one wave per node, index-prefetch + 8-deep gather pipeline ----
// hout[i] = bf16(relu( dinv[i]^2*h[i] + sum_{s in N(i)} dinv[i]*dinv[s]*h[s] + b ))
__global__ __launch_bounds__(256) void k_aggregate(
    const short* __restrict__ h, const float* __restrict__ dinv,
    const int* __restrict__ rowptr, const int* __restrict__ csr_src,
    const float* __restrict__ bias, short* __restrict__ hout, int nN)
{
  const int wave = threadIdx.x >> 6;
  const int lane = threadIdx.x & 63;
  const int node = blockIdx.x*4 + wave;
  if(node >= nN) return;
  const float di = dinv[node];
  const int beg = rowptr[node];
  const int deg = rowptr[node+1] - beg;

  s4v hv = *(const s4v*)&h[(size_t)node*256 + lane*4];
  const float d2 = di*di;
  f4v acc;
  #pragma unroll
  for(int j=0;j<4;j++) acc[j] = d2 * b2f(hv[j]);

  for(int base=0; base<deg; base+=64){
    const int cnt = min(deg - base, 64);
    // cooperative prefetch of indices + degree weights for this chunk
    int   myi = (lane < cnt) ? csr_src[beg + base + lane] : node;
    float myw = (lane < cnt) ? di * dinv[myi] : 0.f;

    for(int p0=0; p0<cnt; p0+=8){
      s4v v[8]; float w[8]; int s[8];
      #pragma unroll
      for(int j=0;j<8;j++){
        int pp = p0 + j;
        int sl = (pp < cnt) ? pp : 0;
        s[j] = __shfl(myi, sl);
        w[j] = (pp < cnt) ? __shfl(myw, sl) : 0.f;
      }
      #pragma unroll
      for(int j=0;j<8;j++)
        v[j] = *(const s4v*)&h[(size_t)s[j]*256 + lane*4];
      #pragma unroll
      for(int j=0;j<8;j++){
        #pragma unroll
        for(int q=0;q<4;q++) acc[q] += w[j] * b2f(v[j][q]);
      }
    }
  }

  f4v bv = *(const f4v*)&bias[lane*4];
  s4v ov;
  #pragma unroll
  for(int j=0;j<4;j++) ov[j] = f2bf(fmaxf(acc[j]+bv[j], 0.f));
  *(s4v*)&hout[(size_t)node*256 + lane*4] = ov;
}

// ---- mean-pool over sorted batch: block = (graph, slice), thread = channel ----
#define POOL_SPLIT 8
__global__ __launch_bounds__(256) void k_pool(const short* __restrict__ h,
    const int* __restrict__ gstart, float* __restrict__ pool, int nG){
  const int g = blockIdx.x;
  const int sl = blockIdx.y;
  const int c = threadIdx.x;
  const int b = gstart[g], e = gstart[g+1];
  const int len = e - b;
  const int r0 = b + (int)((long long)len * sl / POOL_SPLIT);
  const int r1 = b + (int)((long long)len * (sl+1) / POOL_SPLIT);
  float acc = 0.f;
  for(int r=r0; r<r1; r++) acc += b2f(h[(size_t)r*256 + c]);
  if(r1 > r0) atomicAdd(&pool[(size_t)g*256 + c], acc);
}

// out[g][j] = (pool[g]/cnt[g]) @ Wp + bp
__global__ void k_final(const float* __restrict__ pool, const int* __restrict__ gstart,
                        const float* __restrict__ Wp, const float* __restrict__ bp,
                        float* __restrict__ out, int HID_, int OUT_){
  __shared__ float mean[256];
  int g = blockIdx.x, j = threadIdx.x;
  float c = fmaxf((float)(gstart[g+1] - gstart[g]), 1.0f);
  for(int k=j; k<HID_; k+=blockDim.x) mean[k] = pool[(size_t)g*HID_ + k] / c;
  __syncthreads();
  float acc = bp[j];
  for(int k=0;k<HID_;k++) acc = fmaf(mean[k], Wp[(size_t)k*OUT_ + j], acc);
  out[(size_t)g*OUT_ + j] = acc;
}

extern "C" void kernel_launch(void* const* d_in, const int* in_sizes, int n_in,
                              void* d_out, int out_size, void* d_ws, size_t ws_size,
                              hipStream_t stream){
  const float* x   = (const float*)d_in[0];
  const int* ei    = (const int*)d_in[1];
  const int* batch = (const int*)d_in[2];
  const float* W1  = (const float*)d_in[3];
  const float* b1  = (const float*)d_in[4];
  const float* W2  = (const float*)d_in[5];
  const float* b2  = (const float*)d_in[6];
  const float* Wp  = (const float*)d_in[7];
  const float* bp  = (const float*)d_in[8];
  float* out = (float*)d_out;

  const int HID    = in_sizes[4];            // 256
  const int IN_DIM = in_sizes[3] / HID;      // 768
  const int OUT    = in_sizes[8];            // 128
  const int nE     = in_sizes[1] / 2;        // 300000
  const int nN     = in_sizes[2];            // 50000
  const int nG     = out_size / OUT;         // 64

  const int* src = ei;
  const int* tgt = ei + nE;

  char* w = (char*)d_ws;
  size_t off = 0;
  auto alloc = [&](size_t bytes)->char*{
    char* p = w + off; off += (bytes + 511) & ~(size_t)511; return p;
  };
  int*   deg     = (int*)  alloc((size_t)nN*4);
  float* dinv    = (float*)alloc((size_t)nN*4);
  int*   gstart  = (int*)  alloc((size_t)(nG+1)*4);
  float* pool    = (float*)alloc((size_t)nG*HID*4);
  int*   rowptr  = (int*)  alloc((size_t)(nN+1)*4);
  int*   cursor  = (int*)  alloc((size_t)nN*4);
  int*   csr_src = (int*)  alloc((size_t)nE*4);
  int*   blocksum= (int*)  alloc((size_t)1024*4);
  short* W1T     = (short*)alloc((size_t)IN_DIM*HID*2);
  short* W2T     = (short*)alloc((size_t)HID*HID*2);
  short* h1      = (short*)alloc((size_t)nN*HID*2);
  short* h2      = (short*)alloc((size_t)nN*HID*2);
  (void)ws_size; (void)n_in;

  hipMemsetAsync(deg,    0, (size_t)nN*4, stream);
  hipMemsetAsync(cursor, 0, (size_t)nN*4, stream);
  hipMemsetAsync(pool,   0, (size_t)nG*HID*4, stream);

  const int nb = (nN + SCAN_BS - 1) / SCAN_BS;   // 196 blocks
  k_deg <<<(nE+255)/256, 256, 0, stream>>>(tgt, deg, nE);
  k_dinv<<<(nN+255)/256, 256, 0, stream>>>(deg, dinv, nN);
  k_bounds<<<1, ((nG+1+63)/64)*64, 0, stream>>>(batch, gstart, nN, nG);
  k_scan1<<<nb, SCAN_BS, 0, stream>>>(deg, rowptr, blocksum, nN);
  k_scan2<<<1, 1024, 0, stream>>>(blocksum, nb);
  k_scan3<<<nb, SCAN_BS, 0, stream>>>(rowptr, blocksum, nN, nE);
  k_fill <<<(nE+255)/256, 256, 0, stream>>>(src, tgt, rowptr, cursor, csr_src, nE);
  k_transpose_cvt<<<(IN_DIM*HID+255)/256, 256, 0, stream>>>(W1, W1T, IN_DIM, HID);
  k_transpose_cvt<<<(HID*HID+255)/256,   256, 0, stream>>>(W2, W2T, HID, HID);

  dim3 g1((nN+127)/128, HID/128);
  const int nagg = (nN + 3) / 4;
  // layer 1: GEMM -> fused aggregate+bias+relu -> h1
  gemm_bt<true><<<g1, 256, 0, stream>>>(x, W1T, h2, nN, HID, IN_DIM);
  k_aggregate<<<nagg, 256, 0, stream>>>(h2, dinv, rowptr, csr_src, b1, h1, nN);
  // layer 2: GEMM -> fused aggregate+bias+relu -> h2 (reuse buffer) -> pool
  gemm_bt<false><<<g1, 256, 0, stream>>>(h1, W2T, h2, nN, HID, HID);
  k_aggregate<<<nagg, 256, 0, stream>>>(h2, dinv, rowptr, csr_src, b2, h1, nN);
  k_pool<<<dim3(nG, POOL_SPLIT), 256, 0, stream>>>(h1, gstart, pool, nG);
  // head
  k_final<<<nG, OUT, 0, stream>>>(pool, gstart, Wp, bp, out, HID, OUT);
}

// Round 4
// 264.761 us; speedup vs baseline: 9.7817x; 1.0023x over previous
//
#include <hip/hip_runtime.h>
#include <cstdint>
#include <cstddef>

typedef short s8v __attribute__((ext_vector_type(8)));
typedef short s4v __attribute__((ext_vector_type(4)));
typedef float f4v __attribute__((ext_vector_type(4)));

static __device__ __forceinline__ float b2f(short s){
  return __uint_as_float(((uint32_t)(uint16_t)s) << 16);
}
static __device__ __forceinline__ short f2bf(float f){
  uint32_t u = __float_as_uint(f);
  u = (u + 0x7fffu + ((u >> 16) & 1u)) >> 16;
  return (short)(uint16_t)u;
}
// async global->LDS, 16B per lane, LDS dest linear (wave base + lane*16)
static __device__ __forceinline__ void gld_lds16(const void* g, void* l){
  __builtin_amdgcn_global_load_lds((const __attribute__((address_space(1))) void*)g,
                                   (__attribute__((address_space(3))) void*)l, 16, 0, 0);
}

// ---- graph prep ----
__global__ void k_deg(const int* __restrict__ tgt, int* __restrict__ deg, int nE){
  int e = blockIdx.x*blockDim.x + threadIdx.x;
  if(e < nE) atomicAdd(&deg[tgt[e]], 1);
}
__global__ void k_dinv(const int* __restrict__ deg, float* __restrict__ dinv, int nN){
  int i = blockIdx.x*blockDim.x + threadIdx.x;
  if(i < nN) dinv[i] = rsqrtf((float)deg[i] + 1.0f); // +1 self-loop
}
// WT[n][k] = bf16(W[k][n])
__global__ void k_transpose_cvt(const float* __restrict__ W, short* __restrict__ WT, int K, int N){
  int g = blockIdx.x*blockDim.x + threadIdx.x;
  if(g >= K*N) return;
  int n = g / K, k = g % K;
  WT[(size_t)n*K + k] = f2bf(W[(size_t)k*N + n]);
}
// graph boundaries in sorted batch
__global__ void k_bounds(const int* __restrict__ batch, int* __restrict__ gstart,
                         int nN, int nG){
  int g = threadIdx.x;
  if(g > nG) return;
  int lo = 0, hi = nN;
  while(lo < hi){
    int mid = (lo + hi) >> 1;
    if(batch[mid] < g) lo = mid + 1; else hi = mid;
  }
  gstart[g] = lo;
}

// ---- CSR build ----
#define SCAN_BS 256
__global__ void k_scan1(const int* __restrict__ deg, int* __restrict__ rowptr,
                        int* __restrict__ blocksum, int nN){
  __shared__ int tmp[SCAN_BS];
  const int t = threadIdx.x;
  const int i = blockIdx.x*SCAN_BS + t;
  int v = (i < nN) ? deg[i] : 0;
  tmp[t] = v; __syncthreads();
  #pragma unroll
  for(int off=1; off<SCAN_BS; off<<=1){
    int x = (t >= off) ? tmp[t-off] : 0;
    __syncthreads();
    tmp[t] += x;
    __syncthreads();
  }
  if(i < nN) rowptr[i] = tmp[t] - v;
  if(t == SCAN_BS-1) blocksum[blockIdx.x] = tmp[t];
}
__global__ void k_scan2(int* __restrict__ blocksum, int nb){
  __shared__ int tmp[1024];
  const int t = threadIdx.x;
  int v = (t < nb) ? blocksum[t] : 0;
  tmp[t] = v; __syncthreads();
  #pragma unroll
  for(int off=1; off<1024; off<<=1){
    int x = (t >= off) ? tmp[t-off] : 0;
    __syncthreads();
    tmp[t] += x;
    __syncthreads();
  }
  if(t < nb) blocksum[t] = tmp[t] - v;
}
__global__ void k_scan3(int* __restrict__ rowptr, const int* __restrict__ blocksum,
                        int nN, int nE){
  const int i = blockIdx.x*SCAN_BS + threadIdx.x;
  if(i < nN) rowptr[i] += blocksum[blockIdx.x];
  if(i == 0) rowptr[nN] = nE;
}
__global__ void k_fill(const int* __restrict__ src, const int* __restrict__ tgt,
                       const int* __restrict__ rowptr, int* __restrict__ cursor,
                       int* __restrict__ csr_src, float* __restrict__ csr_w,
                       const float* __restrict__ dinv, int nE){
  int e = blockIdx.x*blockDim.x + threadIdx.x;
  if(e >= nE) return;
  int t = tgt[e];
  int s = src[e];
  int pos = rowptr[t] + atomicAdd(&cursor[t], 1);
  csr_src[pos] = s;
  csr_w[pos] = dinv[s] * dinv[t];
}

// ---- streaming GEMM: C[m][n] = sum_k A[m][k]*Bt[n][k], W-chunk stationary in LDS ----
// block: 256 thr (4 waves), tile 128 rows x 128 cols, K in chunks of 128.
// W chunk double-buffered in LDS via global_load_lds with XOR-swizzled source;
// A fragments loaded straight global->reg (each element used once).
template<bool AF32>
__global__ __launch_bounds__(256) void gemm_stream(const void* __restrict__ Ap,
    const short* __restrict__ Bt, short* __restrict__ C, int M, int N, int K)
{
  constexpr int KC = 128;
  __shared__ __align__(16) short Bs[2][128*KC];   // 2 x 32 KB
  const int tid  = threadIdx.x;
  const int lane = tid & 63;
  const int wv   = tid >> 6;     // 0..3
  const int lr   = lane & 15;
  const int hi   = lane >> 4;    // 0..3
  const int blk_row = blockIdx.x * 128;
  const int blk_col = blockIdx.y * 128;
  const int nkc = K / KC;
  const int swz = (lr & 7) << 4; // reader XOR key (row%8 == lr%8 since nf*16 = 0 mod 8)

  f4v acc[2][8];
  #pragma unroll
  for(int s=0;s<2;s++)
    #pragma unroll
    for(int nf=0;nf<8;nf++){ acc[s][nf][0]=0.f; acc[s][nf][1]=0.f; acc[s][nf][2]=0.f; acc[s][nf][3]=0.f; }

  // clamped A row per strip (each wave owns rows wv*32 + s*16 + lr)
  int arow[2];
  #pragma unroll
  for(int s=0;s<2;s++){
    int r = blk_row + wv*32 + s*16 + lr;
    arow[s] = (r < M) ? r : (M-1);
  }

  // stage W chunk kc into Bs[buf]: wave wv stages rows wv*32..wv*32+31 (8 calls x 4 rows)
  auto STAGE = [&](int kc, int buf){
    #pragma unroll
    for(int j=0;j<8;j++){
      const int r0 = wv*32 + j*4;
      const int nl = r0 + hi;                    // row this lane feeds
      const int csrc = lr ^ (nl & 7);            // pre-swizzled source chunk
      const char* g = (const char*)Bt
          + ((size_t)(blk_col + nl) * K + (size_t)kc*KC) * 2 + (csrc << 4);
      gld_lds16(g, (void*)&Bs[buf][r0*KC]);
    }
  };

  STAGE(0, 0);
  __syncthreads();   // drains vmcnt -> buf0 ready

  for(int kc=0; kc<nkc; kc++){
    const int buf = kc & 1;
    if(kc+1 < nkc) STAGE(kc+1, buf^1);

    // hoisted A fragment loads for this K-chunk (4 k-steps x 2 strips)
    s8v a[2][4];
    if constexpr(AF32){
      const float* A = (const float*)Ap;
      #pragma unroll
      for(int s=0;s<2;s++){
        const float* p = A + (size_t)arow[s]*K + kc*KC + hi*8;
        #pragma unroll
        for(int ks=0;ks<4;ks++){
          f4v t0 = *(const f4v*)(p + ks*32);
          f4v t1 = *(const f4v*)(p + ks*32 + 4);
          s8v v;
          #pragma unroll
          for(int q=0;q<4;q++){ v[q] = f2bf(t0[q]); v[4+q] = f2bf(t1[q]); }
          a[s][ks] = v;
        }
      }
    } else {
      const short* A = (const short*)Ap;
      #pragma unroll
      for(int s=0;s<2;s++){
        const short* p = A + (size_t)arow[s]*K + kc*KC + hi*8;
        #pragma unroll
        for(int ks=0;ks<4;ks++) a[s][ks] = *(const s8v*)(p + ks*32);
      }
    }

    const char* base = (const char*)&Bs[buf][0];
    #pragma unroll
    for(int ks=0;ks<4;ks++){
      s8v bfr[8];
      #pragma unroll
      for(int nf=0;nf<8;nf++){
        const int byteoff = ((nf*16 + lr) << 8) + ((((ks*4 + hi) << 4)) ^ swz);
        bfr[nf] = *(const s8v*)(base + byteoff);
      }
      #pragma unroll
      for(int nf=0;nf<8;nf++){
        acc[0][nf] = __builtin_amdgcn_mfma_f32_16x16x32_bf16(a[0][ks], bfr[nf], acc[0][nf], 0, 0, 0);
        acc[1][nf] = __builtin_amdgcn_mfma_f32_16x16x32_bf16(a[1][ks], bfr[nf], acc[1][nf], 0, 0, 0);
      }
    }
    __syncthreads();  // all waves done with Bs[buf]; drains staging of buf^1
  }

  // epilogue: C[row][col], row = blk_row + wv*32 + s*16 + hi*4 + j, col = blk_col + nf*16 + lr
  #pragma unroll
  for(int s=0;s<2;s++){
    #pragma unroll
    for(int j=0;j<4;j++){
      const int row = blk_row + wv*32 + s*16 + hi*4 + j;
      if(row >= M) continue;
      #pragma unroll
      for(int nf=0;nf<8;nf++){
        const int col = blk_col + nf*16 + lr;
        C[(size_t)row*N + col] = f2bf(acc[s][nf][j]);
      }
    }
  }
}

// ---- fused aggregation: one wave per node, coalesced idx/weight prefetch + 8-deep gather ----
__global__ __launch_bounds__(256) void k_aggregate(
    const short* __restrict__ h, const float* __restrict__ dinv,
    const int* __restrict__ rowptr, const int* __restrict__ csr_src,
    const float* __restrict__ csr_w, const float* __restrict__ bias,
    short* __restrict__ hout, int nN)
{
  const int wave = threadIdx.x >> 6;
  const int lane = threadIdx.x & 63;
  const int node = blockIdx.x*4 + wave;
  if(node >= nN) return;
  const float di = dinv[node];
  const int beg = rowptr[node];
  const int deg = rowptr[node+1] - beg;

  s4v hv = *(const s4v*)&h[(size_t)node*256 + lane*4];
  const float d2 = di*di;
  f4v acc;
  #pragma unroll
  for(int j=0;j<4;j++) acc[j] = d2 * b2f(hv[j]);

  for(int base=0; base<deg; base+=64){
    const int cnt = min(deg - base, 64);
    int   myi = (lane < cnt) ? csr_src[beg + base + lane] : 0;
    float myw = (lane < cnt) ? csr_w[beg + base + lane] : 0.f;

    for(int p0=0; p0<cnt; p0+=8){
      s4v v[8]; float w[8]; int s[8];
      #pragma unroll
      for(int j=0;j<8;j++){
        int pp = p0 + j;
        int sl = (pp < cnt) ? pp : 0;
        s[j] = __shfl(myi, sl);
        w[j] = (pp < cnt) ? __shfl(myw, sl) : 0.f;
      }
      #pragma unroll
      for(int j=0;j<8;j++)
        v[j] = *(const s4v*)&h[(size_t)s[j]*256 + lane*4];
      #pragma unroll
      for(int j=0;j<8;j++){
        #pragma unroll
        for(int q=0;q<4;q++) acc[q] += w[j] * b2f(v[j][q]);
      }
    }
  }

  f4v bv = *(const f4v*)&bias[lane*4];
  s4v ov;
  #pragma unroll
  for(int j=0;j<4;j++) ov[j] = f2bf(fmaxf(acc[j]+bv[j], 0.f));
  *(s4v*)&hout[(size_t)node*256 + lane*4] = ov;
}

// ---- mean-pool over sorted batch ----
#define POOL_SPLIT 8
__global__ __launch_bounds__(256) void k_pool(const short* __restrict__ h,
    const int* __restrict__ gstart, float* __restrict__ pool, int nG){
  const int g = blockIdx.x;
  const int sl = blockIdx.y;
  const int c = threadIdx.x;
  const int b = gstart[g], e = gstart[g+1];
  const int len = e - b;
  const int r0 = b + (int)((long long)len * sl / POOL_SPLIT);
  const int r1 = b + (int)((long long)len * (sl+1) / POOL_SPLIT);
  float acc = 0.f;
  for(int r=r0; r<r1; r++) acc += b2f(h[(size_t)r*256 + c]);
  if(r1 > r0) atomicAdd(&pool[(size_t)g*256 + c], acc);
}

__global__ void k_final(const float* __restrict__ pool, const int* __restrict__ gstart,
                        const float* __restrict__ Wp, const float* __restrict__ bp,
                        float* __restrict__ out, int HID_, int OUT_){
  __shared__ float mean[256];
  int g = blockIdx.x, j = threadIdx.x;
  float c = fmaxf((float)(gstart[g+1] - gstart[g]), 1.0f);
  for(int k=j; k<HID_; k+=blockDim.x) mean[k] = pool[(size_t)g*HID_ + k] / c;
  __syncthreads();
  float acc = bp[j];
  for(int k=0;k<HID_;k++) acc = fmaf(mean[k], Wp[(size_t)k*OUT_ + j], acc);
  out[(size_t)g*OUT_ + j] = acc;
}

extern "C" void kernel_launch(void* const* d_in, const int* in_sizes, int n_in,
                              void* d_out, int out_size, void* d_ws, size_t ws_size,
                              hipStream_t stream){
  const float* x   = (const float*)d_in[0];
  const int* ei    = (const int*)d_in[1];
  const int* batch = (const int*)d_in[2];
  const float* W1  = (const float*)d_in[3];
  const float* b1  = (const float*)d_in[4];
  const float* W2  = (const float*)d_in[5];
  const float* b2  = (const float*)d_in[6];
  const float* Wp  = (const float*)d_in[7];
  const float* bp  = (const float*)d_in[8];
  float* out = (float*)d_out;

  const int HID    = in_sizes[4];            // 256
  const int IN_DIM = in_sizes[3] / HID;      // 768
  const int OUT    = in_sizes[8];            // 128
  const int nE     = in_sizes[1] / 2;        // 300000
  const int nN     = in_sizes[2];            // 50000
  const int nG     = out_size / OUT;         // 64

  const int* src = ei;
  const int* tgt = ei + nE;

  char* w = (char*)d_ws;
  size_t off = 0;
  auto alloc = [&](size_t bytes)->char*{
    char* p = w + off; off += (bytes + 511) & ~(size_t)511; return p;
  };
  int*   deg     = (int*)  alloc((size_t)nN*4);
  float* dinv    = (float*)alloc((size_t)nN*4);
  int*   gstart  = (int*)  alloc((size_t)(nG+1)*4);
  float* pool    = (float*)alloc((size_t)nG*HID*4);
  int*   rowptr  = (int*)  alloc((size_t)(nN+1)*4);
  int*   cursor  = (int*)  alloc((size_t)nN*4);
  int*   csr_src = (int*)  alloc((size_t)nE*4);
  float* csr_w   = (float*)alloc((size_t)nE*4);
  int*   blocksum= (int*)  alloc((size_t)1024*4);
  short* W1T     = (short*)alloc((size_t)IN_DIM*HID*2);
  short* W2T     = (short*)alloc((size_t)HID*HID*2);
  short* h1      = (short*)alloc((size_t)nN*HID*2);
  short* h2      = (short*)alloc((size_t)nN*HID*2);
  (void)ws_size; (void)n_in;

  hipMemsetAsync(deg,    0, (size_t)nN*4, stream);
  hipMemsetAsync(cursor, 0, (size_t)nN*4, stream);
  hipMemsetAsync(pool,   0, (size_t)nG*HID*4, stream);

  const int nb = (nN + SCAN_BS - 1) / SCAN_BS;
  k_deg <<<(nE+255)/256, 256, 0, stream>>>(tgt, deg, nE);
  k_dinv<<<(nN+255)/256, 256, 0, stream>>>(deg, dinv, nN);
  k_bounds<<<1, ((nG+1+63)/64)*64, 0, stream>>>(batch, gstart, nN, nG);
  k_scan1<<<nb, SCAN_BS, 0, stream>>>(deg, rowptr, blocksum, nN);
  k_scan2<<<1, 1024, 0, stream>>>(blocksum, nb);
  k_scan3<<<nb, SCAN_BS, 0, stream>>>(rowptr, blocksum, nN, nE);
  k_fill <<<(nE+255)/256, 256, 0, stream>>>(src, tgt, rowptr, cursor, csr_src, csr_w, dinv, nE);
  k_transpose_cvt<<<(IN_DIM*HID+255)/256, 256, 0, stream>>>(W1, W1T, IN_DIM, HID);
  k_transpose_cvt<<<(HID*HID+255)/256,   256, 0, stream>>>(W2, W2T, HID, HID);

  dim3 gg((nN+127)/128, HID/128);
  const int nagg = (nN + 3) / 4;
  // layer 1
  gemm_stream<true><<<gg, 256, 0, stream>>>(x, W1T, h2, nN, HID, IN_DIM);
  k_aggregate<<<nagg, 256, 0, stream>>>(h2, dinv, rowptr, csr_src, csr_w, b1, h1, nN);
  // layer 2
  gemm_stream<false><<<gg, 256, 0, stream>>>(h1, W2T, h2, nN, HID, HID);
  k_aggregate<<<nagg, 256, 0, stream>>>(h2, dinv, rowptr, csr_src, csr_w, b2, h1, nN);
  k_pool<<<dim3(nG, POOL_SPLIT), 256, 0, stream>>>(h1, gstart, pool, nG);
  // head
  k_final<<<nG, OUT, 0, stream>>>(pool, gstart, Wp, bp, out, HID, OUT);
}

// Round 5
// 263.690 us; speedup vs baseline: 9.8215x; 1.0041x over previous
//
#include <hip/hip_runtime.h>
#include <cstdint>
#include <cstddef>

typedef short s8v __attribute__((ext_vector_type(8)));
typedef short s4v __attribute__((ext_vector_type(4)));
typedef float f4v __attribute__((ext_vector_type(4)));

static __device__ __forceinline__ float b2f(short s){
  return __uint_as_float(((uint32_t)(uint16_t)s) << 16);
}
static __device__ __forceinline__ short f2bf(float f){
  uint32_t u = __float_as_uint(f);
  u = (u + 0x7fffu + ((u >> 16) & 1u)) >> 16;
  return (short)(uint16_t)u;
}
// async global->LDS, 16B per lane, LDS dest = uniform base + lane*16
static __device__ __forceinline__ void gld_lds16(const void* g, void* l){
  __builtin_amdgcn_global_load_lds((const __attribute__((address_space(1))) void*)g,
                                   (__attribute__((address_space(3))) void*)l, 16, 0, 0);
}

// ---- graph prep ----
__global__ void k_deg(const int* __restrict__ tgt, int* __restrict__ deg, int nE){
  int e = blockIdx.x*blockDim.x + threadIdx.x;
  if(e < nE) atomicAdd(&deg[tgt[e]], 1);
}
__global__ void k_dinv(const int* __restrict__ deg, float* __restrict__ dinv, int nN){
  int i = blockIdx.x*blockDim.x + threadIdx.x;
  if(i < nN) dinv[i] = rsqrtf((float)deg[i] + 1.0f); // +1 self-loop
}
// WT[n][k] = bf16(W[k][n])
__global__ void k_transpose_cvt(const float* __restrict__ W, short* __restrict__ WT, int K, int N){
  int g = blockIdx.x*blockDim.x + threadIdx.x;
  if(g >= K*N) return;
  int n = g / K, k = g % K;
  WT[(size_t)n*K + k] = f2bf(W[(size_t)k*N + n]);
}
// graph boundaries in sorted batch
__global__ void k_bounds(const int* __restrict__ batch, int* __restrict__ gstart,
                         int nN, int nG){
  int g = threadIdx.x;
  if(g > nG) return;
  int lo = 0, hi = nN;
  while(lo < hi){
    int mid = (lo + hi) >> 1;
    if(batch[mid] < g) lo = mid + 1; else hi = mid;
  }
  gstart[g] = lo;
}

// ---- CSR build ----
#define SCAN_BS 256
__global__ void k_scan1(const int* __restrict__ deg, int* __restrict__ rowptr,
                        int* __restrict__ blocksum, int nN){
  __shared__ int tmp[SCAN_BS];
  const int t = threadIdx.x;
  const int i = blockIdx.x*SCAN_BS + t;
  int v = (i < nN) ? deg[i] : 0;
  tmp[t] = v; __syncthreads();
  #pragma unroll
  for(int off=1; off<SCAN_BS; off<<=1){
    int x = (t >= off) ? tmp[t-off] : 0;
    __syncthreads();
    tmp[t] += x;
    __syncthreads();
  }
  if(i < nN) rowptr[i] = tmp[t] - v;
  if(t == SCAN_BS-1) blocksum[blockIdx.x] = tmp[t];
}
__global__ void k_scan2(int* __restrict__ blocksum, int nb){
  __shared__ int tmp[1024];
  const int t = threadIdx.x;
  int v = (t < nb) ? blocksum[t] : 0;
  tmp[t] = v; __syncthreads();
  #pragma unroll
  for(int off=1; off<1024; off<<=1){
    int x = (t >= off) ? tmp[t-off] : 0;
    __syncthreads();
    tmp[t] += x;
    __syncthreads();
  }
  if(t < nb) blocksum[t] = tmp[t] - v;
}
__global__ void k_scan3(int* __restrict__ rowptr, const int* __restrict__ blocksum,
                        int nN, int nE){
  const int i = blockIdx.x*SCAN_BS + threadIdx.x;
  if(i < nN) rowptr[i] += blocksum[blockIdx.x];
  if(i == 0) rowptr[nN] = nE;
}
__global__ void k_fill(const int* __restrict__ src, const int* __restrict__ tgt,
                       const int* __restrict__ rowptr, int* __restrict__ cursor,
                       int* __restrict__ csr_src, float* __restrict__ csr_w,
                       const float* __restrict__ dinv, int nE){
  int e = blockIdx.x*blockDim.x + threadIdx.x;
  if(e >= nE) return;
  int t = tgt[e];
  int s = src[e];
  int pos = rowptr[t] + atomicAdd(&cursor[t], 1);
  csr_src[pos] = s;
  csr_w[pos] = dinv[s] * dinv[t];
}

// ---- streaming GEMM, all-async-staged ----
// C[m][n] = sum_k A[m][k]*Bt[n][k]. 256 thr (4 waves), tile 128x128, K chunks of 32.
// BOTH A and W chunks double-buffered in LDS via global_load_lds (async, no VGPR cost)
// with XOR-swizzled global source + matching swizzled LDS reads.
// A kept f32 in LDS for layer 1 (converted at fragment read), bf16 for layer 2.
template<bool AF32>
__global__ __launch_bounds__(256) void gemm_stream(const void* __restrict__ Ap,
    const short* __restrict__ Bt, short* __restrict__ C, int M, int N, int K)
{
  constexpr int KC = 32;
  constexpr int ESZ = AF32 ? 4 : 2;
  constexpr int AB  = KC * ESZ;          // A bytes per row: 128 | 64
  constexpr int ACPR = AB / 16;          // 16B chunks per A row: 8 | 4
  constexpr int ARPC = 64 / ACPR;        // rows per gld_lds call: 8 | 16
  __shared__ __align__(16) char As[2][128*AB];   // f32: 2x16KB, bf16: 2x8KB
  __shared__ __align__(16) char Bs[2][128*64];   // 2x8KB
  const int tid  = threadIdx.x;
  const int lane = tid & 63;
  const int wv   = tid >> 6;
  const int lr   = lane & 15;
  const int hi   = lane >> 4;
  const int blk_row = blockIdx.x * 128;
  const int blk_col = blockIdx.y * 128;
  const int nkc = K / KC;

  f4v acc[2][8];
  #pragma unroll
  for(int s=0;s<2;s++)
    #pragma unroll
    for(int nf=0;nf<8;nf++){ acc[s][nf][0]=0.f; acc[s][nf][1]=0.f; acc[s][nf][2]=0.f; acc[s][nf][3]=0.f; }

  // staging lane geometry
  const int a_ch = lane & (ACPR-1);
  const int a_ro = lane / ACPR;
  const int w_ch = lane & 3;
  const int w_ro = lane >> 2;

  auto STAGE = [&](int kc, int buf){
    // A: wave wv stages rows [wv*32, wv*32+32)
    #pragma unroll
    for(int j=0; j<32/ARPC; j++){
      const int base_row = wv*32 + j*ARPC;
      const int lrow = base_row + a_ro;
      int grow = blk_row + lrow; if(grow >= M) grow = M-1;
      int sch;
      if constexpr(AF32) sch = a_ch ^ (lrow & 7);
      else               sch = a_ch ^ ((lrow>>1) & 3);
      const char* g = (const char*)Ap + ((size_t)grow*K + (size_t)kc*KC)*ESZ + (sch<<4);
      gld_lds16(g, (void*)(As[buf] + base_row*AB));
    }
    // W: wave wv stages rows [wv*32, wv*32+32), 16 rows per call
    #pragma unroll
    for(int j=0; j<2; j++){
      const int base_row = wv*32 + j*16;
      const int lrow = base_row + w_ro;
      const int sch = w_ch ^ ((lrow>>1) & 3);
      const char* g = (const char*)Bt + ((size_t)(blk_col + lrow)*K + (size_t)kc*KC)*2 + (sch<<4);
      gld_lds16(g, (void*)(Bs[buf] + base_row*64));
    }
  };

  STAGE(0, 0);
  __syncthreads();   // per-wave vmcnt drain + barrier: buf0 ready for all

  for(int kc=0; kc<nkc; kc++){
    const int buf = kc & 1;
    if(kc+1 < nkc) STAGE(kc+1, buf^1);   // async, in flight during compute

    const char* ab = As[buf];
    const char* bb = Bs[buf];

    // A fragments (k = hi*8 .. hi*8+7)
    s8v a[2];
    #pragma unroll
    for(int s=0;s<2;s++){
      const int row = wv*32 + s*16 + lr;
      if constexpr(AF32){
        const int c0 = (2*hi)   ^ (row & 7);
        const int c1 = (2*hi+1) ^ (row & 7);
        f4v lo  = *(const f4v*)(ab + row*128 + (c0<<4));
        f4v hi4 = *(const f4v*)(ab + row*128 + (c1<<4));
        s8v v;
        #pragma unroll
        for(int q=0;q<4;q++){ v[q] = f2bf(lo[q]); v[4+q] = f2bf(hi4[q]); }
        a[s] = v;
      } else {
        const int c = hi ^ ((row>>1) & 3);
        a[s] = *(const s8v*)(ab + row*64 + (c<<4));
      }
    }

    #pragma unroll
    for(int nf=0;nf<8;nf++){
      const int brow = nf*16 + lr;
      const int c = hi ^ ((brow>>1) & 3);
      s8v bfr = *(const s8v*)(bb + brow*64 + (c<<4));
      acc[0][nf] = __builtin_amdgcn_mfma_f32_16x16x32_bf16(a[0], bfr, acc[0][nf], 0, 0, 0);
      acc[1][nf] = __builtin_amdgcn_mfma_f32_16x16x32_bf16(a[1], bfr, acc[1][nf], 0, 0, 0);
    }
    __syncthreads();  // drains own staging vmcnt; next buf ready after barrier
  }

  // epilogue: row = blk_row + wv*32 + s*16 + hi*4 + j, col = blk_col + nf*16 + lr
  #pragma unroll
  for(int s=0;s<2;s++){
    #pragma unroll
    for(int j=0;j<4;j++){
      const int row = blk_row + wv*32 + s*16 + hi*4 + j;
      if(row >= M) continue;
      #pragma unroll
      for(int nf=0;nf<8;nf++){
        const int col = blk_col + nf*16 + lr;
        C[(size_t)row*N + col] = f2bf(acc[s][nf][j]);
      }
    }
  }
}

// ---- fused aggregation: one wave per node, coalesced idx/weight prefetch + 8-deep gather ----
__global__ __launch_bounds__(256) void k_aggregate(
    const short* __restrict__ h, const float* __restrict__ dinv,
    const int* __restrict__ rowptr, const int* __restrict__ csr_src,
    const float* __restrict__ csr_w, const float* __restrict__ bias,
    short* __restrict__ hout, int nN)
{
  const int wave = threadIdx.x >> 6;
  const int lane = threadIdx.x & 63;
  const int node = blockIdx.x*4 + wave;
  if(node >= nN) return;
  const float di = dinv[node];
  const int beg = rowptr[node];
  const int deg = rowptr[node+1] - beg;

  s4v hv = *(const s4v*)&h[(size_t)node*256 + lane*4];
  const float d2 = di*di;
  f4v acc;
  #pragma unroll
  for(int j=0;j<4;j++) acc[j] = d2 * b2f(hv[j]);

  for(int base=0; base<deg; base+=64){
    const int cnt = min(deg - base, 64);
    int   myi = (lane < cnt) ? csr_src[beg + base + lane] : 0;
    float myw = (lane < cnt) ? csr_w[beg + base + lane] : 0.f;

    for(int p0=0; p0<cnt; p0+=8){
      s4v v[8]; float w[8]; int s[8];
      #pragma unroll
      for(int j=0;j<8;j++){
        int pp = p0 + j;
        int sl = (pp < cnt) ? pp : 0;
        s[j] = __shfl(myi, sl);
        w[j] = (pp < cnt) ? __shfl(myw, sl) : 0.f;
      }
      #pragma unroll
      for(int j=0;j<8;j++)
        v[j] = *(const s4v*)&h[(size_t)s[j]*256 + lane*4];
      #pragma unroll
      for(int j=0;j<8;j++){
        #pragma unroll
        for(int q=0;q<4;q++) acc[q] += w[j] * b2f(v[j][q]);
      }
    }
  }

  f4v bv = *(const f4v*)&bias[lane*4];
  s4v ov;
  #pragma unroll
  for(int j=0;j<4;j++) ov[j] = f2bf(fmaxf(acc[j]+bv[j], 0.f));
  *(s4v*)&hout[(size_t)node*256 + lane*4] = ov;
}

// ---- mean-pool over sorted batch ----
#define POOL_SPLIT 8
__global__ __launch_bounds__(256) void k_pool(const short* __restrict__ h,
    const int* __restrict__ gstart, float* __restrict__ pool, int nG){
  const int g = blockIdx.x;
  const int sl = blockIdx.y;
  const int c = threadIdx.x;
  const int b = gstart[g], e = gstart[g+1];
  const int len = e - b;
  const int r0 = b + (int)((long long)len * sl / POOL_SPLIT);
  const int r1 = b + (int)((long long)len * (sl+1) / POOL_SPLIT);
  float acc = 0.f;
  for(int r=r0; r<r1; r++) acc += b2f(h[(size_t)r*256 + c]);
  if(r1 > r0) atomicAdd(&pool[(size_t)g*256 + c], acc);
}

__global__ void k_final(const float* __restrict__ pool, const int* __restrict__ gstart,
                        const float* __restrict__ Wp, const float* __restrict__ bp,
                        float* __restrict__ out, int HID_, int OUT_){
  __shared__ float mean[256];
  int g = blockIdx.x, j = threadIdx.x;
  float c = fmaxf((float)(gstart[g+1] - gstart[g]), 1.0f);
  for(int k=j; k<HID_; k+=blockDim.x) mean[k] = pool[(size_t)g*HID_ + k] / c;
  __syncthreads();
  float acc = bp[j];
  for(int k=0;k<HID_;k++) acc = fmaf(mean[k], Wp[(size_t)k*OUT_ + j], acc);
  out[(size_t)g*OUT_ + j] = acc;
}

extern "C" void kernel_launch(void* const* d_in, const int* in_sizes, int n_in,
                              void* d_out, int out_size, void* d_ws, size_t ws_size,
                              hipStream_t stream){
  const float* x   = (const float*)d_in[0];
  const int* ei    = (const int*)d_in[1];
  const int* batch = (const int*)d_in[2];
  const float* W1  = (const float*)d_in[3];
  const float* b1  = (const float*)d_in[4];
  const float* W2  = (const float*)d_in[5];
  const float* b2  = (const float*)d_in[6];
  const float* Wp  = (const float*)d_in[7];
  const float* bp  = (const float*)d_in[8];
  float* out = (float*)d_out;

  const int HID    = in_sizes[4];            // 256
  const int IN_DIM = in_sizes[3] / HID;      // 768
  const int OUT    = in_sizes[8];            // 128
  const int nE     = in_sizes[1] / 2;        // 300000
  const int nN     = in_sizes[2];            // 50000
  const int nG     = out_size / OUT;         // 64

  const int* src = ei;
  const int* tgt = ei + nE;

  char* w = (char*)d_ws;
  size_t off = 0;
  auto alloc = [&](size_t bytes)->char*{
    char* p = w + off; off += (bytes + 511) & ~(size_t)511; return p;
  };
  int*   deg     = (int*)  alloc((size_t)nN*4);
  float* dinv    = (float*)alloc((size_t)nN*4);
  int*   gstart  = (int*)  alloc((size_t)(nG+1)*4);
  float* pool    = (float*)alloc((size_t)nG*HID*4);
  int*   rowptr  = (int*)  alloc((size_t)(nN+1)*4);
  int*   cursor  = (int*)  alloc((size_t)nN*4);
  int*   csr_src = (int*)  alloc((size_t)nE*4);
  float* csr_w   = (float*)alloc((size_t)nE*4);
  int*   blocksum= (int*)  alloc((size_t)1024*4);
  short* W1T     = (short*)alloc((size_t)IN_DIM*HID*2);
  short* W2T     = (short*)alloc((size_t)HID*HID*2);
  short* h1      = (short*)alloc((size_t)nN*HID*2);
  short* h2      = (short*)alloc((size_t)nN*HID*2);
  (void)ws_size; (void)n_in;

  hipMemsetAsync(deg,    0, (size_t)nN*4, stream);
  hipMemsetAsync(cursor, 0, (size_t)nN*4, stream);
  hipMemsetAsync(pool,   0, (size_t)nG*HID*4, stream);

  const int nb = (nN + SCAN_BS - 1) / SCAN_BS;
  k_deg <<<(nE+255)/256, 256, 0, stream>>>(tgt, deg, nE);
  k_dinv<<<(nN+255)/256, 256, 0, stream>>>(deg, dinv, nN);
  k_bounds<<<1, ((nG+1+63)/64)*64, 0, stream>>>(batch, gstart, nN, nG);
  k_scan1<<<nb, SCAN_BS, 0, stream>>>(deg, rowptr, blocksum, nN);
  k_scan2<<<1, 1024, 0, stream>>>(blocksum, nb);
  k_scan3<<<nb, SCAN_BS, 0, stream>>>(rowptr, blocksum, nN, nE);
  k_fill <<<(nE+255)/256, 256, 0, stream>>>(src, tgt, rowptr, cursor, csr_src, csr_w, dinv, nE);
  k_transpose_cvt<<<(IN_DIM*HID+255)/256, 256, 0, stream>>>(W1, W1T, IN_DIM, HID);
  k_transpose_cvt<<<(HID*HID+255)/256,   256, 0, stream>>>(W2, W2T, HID, HID);

  dim3 gg((nN+127)/128, HID/128);
  const int nagg = (nN + 3) / 4;
  // layer 1
  gemm_stream<true><<<gg, 256, 0, stream>>>(x, W1T, h2, nN, HID, IN_DIM);
  k_aggregate<<<nagg, 256, 0, stream>>>(h2, dinv, rowptr, csr_src, csr_w, b1, h1, nN);
  // layer 2
  gemm_stream<false><<<gg, 256, 0, stream>>>(h1, W2T, h2, nN, HID, HID);
  k_aggregate<<<nagg, 256, 0, stream>>>(h2, dinv, rowptr, csr_src, csr_w, b2, h1, nN);
  k_pool<<<dim3(nG, POOL_SPLIT), 256, 0, stream>>>(h1, gstart, pool, nG);
  // head
  k_final<<<nG, OUT, 0, stream>>>(pool, gstart, Wp, bp, out, HID, OUT);
}

// Round 6
// 253.035 us; speedup vs baseline: 10.2350x; 1.0421x over previous
//
#include <hip/hip_runtime.h>
#include <cstdint>
#include <cstddef>

typedef short s8v __attribute__((ext_vector_type(8)));
typedef short s4v __attribute__((ext_vector_type(4)));
typedef float f4v __attribute__((ext_vector_type(4)));

static __device__ __forceinline__ float b2f(short s){
  return __uint_as_float(((uint32_t)(uint16_t)s) << 16);
}
static __device__ __forceinline__ short f2bf(float f){
  uint32_t u = __float_as_uint(f);
  u = (u + 0x7fffu + ((u >> 16) & 1u)) >> 16;
  return (short)(uint16_t)u;
}
// async global->LDS, 16B per lane, LDS dest = uniform base + lane*16
static __device__ __forceinline__ void gld_lds16(const void* g, void* l){
  __builtin_amdgcn_global_load_lds((const __attribute__((address_space(1))) void*)g,
                                   (__attribute__((address_space(3))) void*)l, 16, 0, 0);
}

// ---- graph prep ----
__global__ void k_deg(const int* __restrict__ tgt, int* __restrict__ deg, int nE){
  int e = blockIdx.x*blockDim.x + threadIdx.x;
  if(e < nE) atomicAdd(&deg[tgt[e]], 1);
}
__global__ void k_dinv(const int* __restrict__ deg, float* __restrict__ dinv, int nN){
  int i = blockIdx.x*blockDim.x + threadIdx.x;
  if(i < nN) dinv[i] = rsqrtf((float)deg[i] + 1.0f); // +1 self-loop
}
// WT[n][k] = bf16(W[k][n])
__global__ void k_transpose_cvt(const float* __restrict__ W, short* __restrict__ WT, int K, int N){
  int g = blockIdx.x*blockDim.x + threadIdx.x;
  if(g >= K*N) return;
  int n = g / K, k = g % K;
  WT[(size_t)n*K + k] = f2bf(W[(size_t)k*N + n]);
}
// graph boundaries in sorted batch
__global__ void k_bounds(const int* __restrict__ batch, int* __restrict__ gstart,
                         int nN, int nG){
  int g = threadIdx.x;
  if(g > nG) return;
  int lo = 0, hi = nN;
  while(lo < hi){
    int mid = (lo + hi) >> 1;
    if(batch[mid] < g) lo = mid + 1; else hi = mid;
  }
  gstart[g] = lo;
}

// ---- CSR build ----
#define SCAN_BS 256
__global__ void k_scan1(const int* __restrict__ deg, int* __restrict__ rowptr,
                        int* __restrict__ blocksum, int nN){
  __shared__ int tmp[SCAN_BS];
  const int t = threadIdx.x;
  const int i = blockIdx.x*SCAN_BS + t;
  int v = (i < nN) ? deg[i] : 0;
  tmp[t] = v; __syncthreads();
  #pragma unroll
  for(int off=1; off<SCAN_BS; off<<=1){
    int x = (t >= off) ? tmp[t-off] : 0;
    __syncthreads();
    tmp[t] += x;
    __syncthreads();
  }
  if(i < nN) rowptr[i] = tmp[t] - v;
  if(t == SCAN_BS-1) blocksum[blockIdx.x] = tmp[t];
}
__global__ void k_scan2(int* __restrict__ blocksum, int nb){
  __shared__ int tmp[1024];
  const int t = threadIdx.x;
  int v = (t < nb) ? blocksum[t] : 0;
  tmp[t] = v; __syncthreads();
  #pragma unroll
  for(int off=1; off<1024; off<<=1){
    int x = (t >= off) ? tmp[t-off] : 0;
    __syncthreads();
    tmp[t] += x;
    __syncthreads();
  }
  if(t < nb) blocksum[t] = tmp[t] - v;
}
__global__ void k_scan3(int* __restrict__ rowptr, const int* __restrict__ blocksum,
                        int nN, int nE){
  const int i = blockIdx.x*SCAN_BS + threadIdx.x;
  if(i < nN) rowptr[i] += blocksum[blockIdx.x];
  if(i == 0) rowptr[nN] = nE;
}
__global__ void k_fill(const int* __restrict__ src, const int* __restrict__ tgt,
                       const int* __restrict__ rowptr, int* __restrict__ cursor,
                       int* __restrict__ csr_src, float* __restrict__ csr_w,
                       const float* __restrict__ dinv, int nE){
  int e = blockIdx.x*blockDim.x + threadIdx.x;
  if(e >= nE) return;
  int t = tgt[e];
  int s = src[e];
  int pos = rowptr[t] + atomicAdd(&cursor[t], 1);
  csr_src[pos] = s;
  csr_w[pos] = dinv[s] * dinv[t];
}

// ---- streaming GEMM, async-staged, counted-vmcnt pipeline (T4) ----
// C[m][n] = sum_k A[m][k]*Bt[n][k]. 256 thr (4 waves), tile 128x128, K chunks of 32.
// A and W staged via global_load_lds into a 3-buffer rotation. Per iteration:
//   STAGE(kc+1) ; s_waitcnt vmcnt(NSTG) [never 0 in-loop] ; s_barrier ; compute(kc)
// Buffer safety (depth-1, B=3): chunk kc+1's LDS writes land while readers
// use slots {kc-1, kc} mod 3 — distinct from (kc+1) mod 3. One barrier/iter
// bounds wave skew; each wave drains its own loads pre-barrier so shared W
// rows are visible after it.
template<bool AF32>
__global__ __launch_bounds__(256) void gemm_stream(const void* __restrict__ Ap,
    const short* __restrict__ Bt, short* __restrict__ C, int M, int N, int K)
{
  constexpr int KC = 32;
  constexpr int ESZ = AF32 ? 4 : 2;
  constexpr int AB  = KC * ESZ;          // A bytes per row: 128 | 64
  constexpr int ACPR = AB / 16;          // 16B chunks per A row: 8 | 4
  constexpr int ARPC = 64 / ACPR;        // rows per gld_lds call: 8 | 16
  __shared__ __align__(16) char As[3][128*AB];   // f32: 3x16KB, bf16: 3x8KB
  __shared__ __align__(16) char Bs[3][128*64];   // 3x8KB
  const int tid  = threadIdx.x;
  const int lane = tid & 63;
  const int wv   = tid >> 6;
  const int lr   = lane & 15;
  const int hi   = lane >> 4;
  const int blk_row = blockIdx.x * 128;
  const int blk_col = blockIdx.y * 128;
  const int nkc = K / KC;

  f4v acc[2][8];
  #pragma unroll
  for(int s=0;s<2;s++)
    #pragma unroll
    for(int nf=0;nf<8;nf++){ acc[s][nf][0]=0.f; acc[s][nf][1]=0.f; acc[s][nf][2]=0.f; acc[s][nf][3]=0.f; }

  // staging lane geometry
  const int a_ch = lane & (ACPR-1);
  const int a_ro = lane / ACPR;
  const int w_ch = lane & 3;
  const int w_ro = lane >> 2;

  auto STAGE = [&](int kc, int buf){
    // A: wave wv stages rows [wv*32, wv*32+32)
    #pragma unroll
    for(int j=0; j<32/ARPC; j++){
      const int base_row = wv*32 + j*ARPC;
      const int lrow = base_row + a_ro;
      int grow = blk_row + lrow; if(grow >= M) grow = M-1;
      int sch;
      if constexpr(AF32) sch = a_ch ^ (lrow & 7);
      else               sch = a_ch ^ ((lrow>>1) & 3);
      const char* g = (const char*)Ap + ((size_t)grow*K + (size_t)kc*KC)*ESZ + (sch<<4);
      gld_lds16(g, (void*)(As[buf] + base_row*AB));
    }
    // W: wave wv stages rows [wv*32, wv*32+32), 16 rows per call
    #pragma unroll
    for(int j=0; j<2; j++){
      const int base_row = wv*32 + j*16;
      const int lrow = base_row + w_ro;
      const int sch = w_ch ^ ((lrow>>1) & 3);
      const char* g = (const char*)Bt + ((size_t)(blk_col + lrow)*K + (size_t)kc*KC)*2 + (sch<<4);
      gld_lds16(g, (void*)(Bs[buf] + base_row*64));
    }
  };

  STAGE(0, 0);   // NSTG per-wave loads in flight

  for(int kc=0; kc<nkc; kc++){
    const int buf = kc % 3;
    if(kc+1 < nkc){
      STAGE(kc+1, (kc+1) % 3);   // now 2*NSTG outstanding
      // drain chunk kc only; keep chunk kc+1 in flight across the barrier
      if constexpr(AF32) asm volatile("s_waitcnt vmcnt(6)" ::: "memory");
      else               asm volatile("s_waitcnt vmcnt(4)" ::: "memory");
    } else {
      asm volatile("s_waitcnt vmcnt(0)" ::: "memory");
    }
    __builtin_amdgcn_s_barrier();
    __builtin_amdgcn_sched_barrier(0);

    const char* ab = As[buf];
    const char* bb = Bs[buf];

    // A fragments (k = hi*8 .. hi*8+7)
    s8v a[2];
    #pragma unroll
    for(int s=0;s<2;s++){
      const int row = wv*32 + s*16 + lr;
      if constexpr(AF32){
        const int c0 = (2*hi)   ^ (row & 7);
        const int c1 = (2*hi+1) ^ (row & 7);
        f4v lo  = *(const f4v*)(ab + row*128 + (c0<<4));
        f4v hi4 = *(const f4v*)(ab + row*128 + (c1<<4));
        s8v v;
        #pragma unroll
        for(int q=0;q<4;q++){ v[q] = f2bf(lo[q]); v[4+q] = f2bf(hi4[q]); }
        a[s] = v;
      } else {
        const int c = hi ^ ((row>>1) & 3);
        a[s] = *(const s8v*)(ab + row*64 + (c<<4));
      }
    }

    #pragma unroll
    for(int nf=0;nf<8;nf++){
      const int brow = nf*16 + lr;
      const int c = hi ^ ((brow>>1) & 3);
      s8v bfr = *(const s8v*)(bb + brow*64 + (c<<4));
      acc[0][nf] = __builtin_amdgcn_mfma_f32_16x16x32_bf16(a[0], bfr, acc[0][nf], 0, 0, 0);
      acc[1][nf] = __builtin_amdgcn_mfma_f32_16x16x32_bf16(a[1], bfr, acc[1][nf], 0, 0, 0);
    }
    // no trailing barrier: next iteration's STAGE writes slot (kc+2)%3,
    // readers are at slots {kc, kc+1}%3 — distinct.
  }

  // epilogue: row = blk_row + wv*32 + s*16 + hi*4 + j, col = blk_col + nf*16 + lr
  #pragma unroll
  for(int s=0;s<2;s++){
    #pragma unroll
    for(int j=0;j<4;j++){
      const int row = blk_row + wv*32 + s*16 + hi*4 + j;
      if(row >= M) continue;
      #pragma unroll
      for(int nf=0;nf<8;nf++){
        const int col = blk_col + nf*16 + lr;
        C[(size_t)row*N + col] = f2bf(acc[s][nf][j]);
      }
    }
  }
}

// ---- fused aggregation: one wave per node, coalesced idx/weight prefetch + 8-deep gather ----
__global__ __launch_bounds__(256) void k_aggregate(
    const short* __restrict__ h, const float* __restrict__ dinv,
    const int* __restrict__ rowptr, const int* __restrict__ csr_src,
    const float* __restrict__ csr_w, const float* __restrict__ bias,
    short* __restrict__ hout, int nN)
{
  const int wave = threadIdx.x >> 6;
  const int lane = threadIdx.x & 63;
  const int node = blockIdx.x*4 + wave;
  if(node >= nN) return;
  const float di = dinv[node];
  const int beg = rowptr[node];
  const int deg = rowptr[node+1] - beg;

  s4v hv = *(const s4v*)&h[(size_t)node*256 + lane*4];
  const float d2 = di*di;
  f4v acc;
  #pragma unroll
  for(int j=0;j<4;j++) acc[j] = d2 * b2f(hv[j]);

  for(int base=0; base<deg; base+=64){
    const int cnt = min(deg - base, 64);
    int   myi = (lane < cnt) ? csr_src[beg + base + lane] : 0;
    float myw = (lane < cnt) ? csr_w[beg + base + lane] : 0.f;

    for(int p0=0; p0<cnt; p0+=8){
      s4v v[8]; float w[8]; int s[8];
      #pragma unroll
      for(int j=0;j<8;j++){
        int pp = p0 + j;
        int sl = (pp < cnt) ? pp : 0;
        s[j] = __shfl(myi, sl);
        w[j] = (pp < cnt) ? __shfl(myw, sl) : 0.f;
      }
      #pragma unroll
      for(int j=0;j<8;j++)
        v[j] = *(const s4v*)&h[(size_t)s[j]*256 + lane*4];
      #pragma unroll
      for(int j=0;j<8;j++){
        #pragma unroll
        for(int q=0;q<4;q++) acc[q] += w[j] * b2f(v[j][q]);
      }
    }
  }

  f4v bv = *(const f4v*)&bias[lane*4];
  s4v ov;
  #pragma unroll
  for(int j=0;j<4;j++) ov[j] = f2bf(fmaxf(acc[j]+bv[j], 0.f));
  *(s4v*)&hout[(size_t)node*256 + lane*4] = ov;
}

// ---- mean-pool over sorted batch ----
#define POOL_SPLIT 8
__global__ __launch_bounds__(256) void k_pool(const short* __restrict__ h,
    const int* __restrict__ gstart, float* __restrict__ pool, int nG){
  const int g = blockIdx.x;
  const int sl = blockIdx.y;
  const int c = threadIdx.x;
  const int b = gstart[g], e = gstart[g+1];
  const int len = e - b;
  const int r0 = b + (int)((long long)len * sl / POOL_SPLIT);
  const int r1 = b + (int)((long long)len * (sl+1) / POOL_SPLIT);
  float acc = 0.f;
  for(int r=r0; r<r1; r++) acc += b2f(h[(size_t)r*256 + c]);
  if(r1 > r0) atomicAdd(&pool[(size_t)g*256 + c], acc);
}

__global__ void k_final(const float* __restrict__ pool, const int* __restrict__ gstart,
                        const float* __restrict__ Wp, const float* __restrict__ bp,
                        float* __restrict__ out, int HID_, int OUT_){
  __shared__ float mean[256];
  int g = blockIdx.x, j = threadIdx.x;
  float c = fmaxf((float)(gstart[g+1] - gstart[g]), 1.0f);
  for(int k=j; k<HID_; k+=blockDim.x) mean[k] = pool[(size_t)g*HID_ + k] / c;
  __syncthreads();
  float acc = bp[j];
  for(int k=0;k<HID_;k++) acc = fmaf(mean[k], Wp[(size_t)k*OUT_ + j], acc);
  out[(size_t)g*OUT_ + j] = acc;
}

extern "C" void kernel_launch(void* const* d_in, const int* in_sizes, int n_in,
                              void* d_out, int out_size, void* d_ws, size_t ws_size,
                              hipStream_t stream){
  const float* x   = (const float*)d_in[0];
  const int* ei    = (const int*)d_in[1];
  const int* batch = (const int*)d_in[2];
  const float* W1  = (const float*)d_in[3];
  const float* b1  = (const float*)d_in[4];
  const float* W2  = (const float*)d_in[5];
  const float* b2  = (const float*)d_in[6];
  const float* Wp  = (const float*)d_in[7];
  const float* bp  = (const float*)d_in[8];
  float* out = (float*)d_out;

  const int HID    = in_sizes[4];            // 256
  const int IN_DIM = in_sizes[3] / HID;      // 768
  const int OUT    = in_sizes[8];            // 128
  const int nE     = in_sizes[1] / 2;        // 300000
  const int nN     = in_sizes[2];            // 50000
  const int nG     = out_size / OUT;         // 64

  const int* src = ei;
  const int* tgt = ei + nE;

  char* w = (char*)d_ws;
  size_t off = 0;
  auto alloc = [&](size_t bytes)->char*{
    char* p = w + off; off += (bytes + 511) & ~(size_t)511; return p;
  };
  int*   deg     = (int*)  alloc((size_t)nN*4);
  float* dinv    = (float*)alloc((size_t)nN*4);
  int*   gstart  = (int*)  alloc((size_t)(nG+1)*4);
  float* pool    = (float*)alloc((size_t)nG*HID*4);
  int*   rowptr  = (int*)  alloc((size_t)(nN+1)*4);
  int*   cursor  = (int*)  alloc((size_t)nN*4);
  int*   csr_src = (int*)  alloc((size_t)nE*4);
  float* csr_w   = (float*)alloc((size_t)nE*4);
  int*   blocksum= (int*)  alloc((size_t)1024*4);
  short* W1T     = (short*)alloc((size_t)IN_DIM*HID*2);
  short* W2T     = (short*)alloc((size_t)HID*HID*2);
  short* h1      = (short*)alloc((size_t)nN*HID*2);
  short* h2      = (short*)alloc((size_t)nN*HID*2);
  (void)ws_size; (void)n_in;

  hipMemsetAsync(deg,    0, (size_t)nN*4, stream);
  hipMemsetAsync(cursor, 0, (size_t)nN*4, stream);
  hipMemsetAsync(pool,   0, (size_t)nG*HID*4, stream);

  const int nb = (nN + SCAN_BS - 1) / SCAN_BS;
  k_deg <<<(nE+255)/256, 256, 0, stream>>>(tgt, deg, nE);
  k_dinv<<<(nN+255)/256, 256, 0, stream>>>(deg, dinv, nN);
  k_bounds<<<1, ((nG+1+63)/64)*64, 0, stream>>>(batch, gstart, nN, nG);
  k_scan1<<<nb, SCAN_BS, 0, stream>>>(deg, rowptr, blocksum, nN);
  k_scan2<<<1, 1024, 0, stream>>>(blocksum, nb);
  k_scan3<<<nb, SCAN_BS, 0, stream>>>(rowptr, blocksum, nN, nE);
  k_fill <<<(nE+255)/256, 256, 0, stream>>>(src, tgt, rowptr, cursor, csr_src, csr_w, dinv, nE);
  k_transpose_cvt<<<(IN_DIM*HID+255)/256, 256, 0, stream>>>(W1, W1T, IN_DIM, HID);
  k_transpose_cvt<<<(HID*HID+255)/256,   256, 0, stream>>>(W2, W2T, HID, HID);

  dim3 gg((nN+127)/128, HID/128);
  const int nagg = (nN + 3) / 4;
  // layer 1
  gemm_stream<true><<<gg, 256, 0, stream>>>(x, W1T, h2, nN, HID, IN_DIM);
  k_aggregate<<<nagg, 256, 0, stream>>>(h2, dinv, rowptr, csr_src, csr_w, b1, h1, nN);
  // layer 2
  gemm_stream<false><<<gg, 256, 0, stream>>>(h1, W2T, h2, nN, HID, HID);
  k_aggregate<<<nagg, 256, 0, stream>>>(h2, dinv, rowptr, csr_src, csr_w, b2, h1, nN);
  k_pool<<<dim3(nG, POOL_SPLIT), 256, 0, stream>>>(h1, gstart, pool, nG);
  // head
  k_final<<<nG, OUT, 0, stream>>>(pool, gstart, Wp, bp, out, HID, OUT);
}